// Round 1
// baseline (2393.165 us; speedup 1.0000x reference)
//
#include <hip/hip_runtime.h>
#include <math.h>

#define NB   16
#define NTOK 577
#define CDIM 768
#define NH   12
#define HD   64
#define HID  3072
#define RTOT (NB*NTOK)   // 9232

// ---------------------------------------------------------------------------
// LayerNorm: one 256-thread block per row (768 elems, 3 per thread)
// ---------------------------------------------------------------------------
__global__ __launch_bounds__(256) void ln_kernel(
    const float* __restrict__ x, const float* __restrict__ g,
    const float* __restrict__ b, float* __restrict__ out)
{
    int row = blockIdx.x;
    const float* xr = x + (size_t)row * CDIM;
    float* orow = out + (size_t)row * CDIM;
    int t = threadIdx.x;
    float v0 = xr[t], v1 = xr[t + 256], v2 = xr[t + 512];
    float s  = v0 + v1 + v2;
    float s2 = v0*v0 + v1*v1 + v2*v2;
    #pragma unroll
    for (int off = 32; off; off >>= 1) {
        s  += __shfl_xor(s, off);
        s2 += __shfl_xor(s2, off);
    }
    __shared__ float red[10];
    int wave = t >> 6, lane = t & 63;
    if (lane == 0) { red[wave] = s; red[wave + 4] = s2; }
    __syncthreads();
    if (t == 0) {
        float ts  = red[0] + red[1] + red[2] + red[3];
        float ts2 = red[4] + red[5] + red[6] + red[7];
        float mu  = ts * (1.0f / CDIM);
        float var = ts2 * (1.0f / CDIM) - mu * mu;
        red[8] = mu;
        red[9] = rsqrtf(var + 1e-5f);
    }
    __syncthreads();
    float mu = red[8], rs = red[9];
    orow[t]       = (v0 - mu) * rs * g[t]       + b[t];
    orow[t + 256] = (v1 - mu) * rs * g[t + 256] + b[t + 256];
    orow[t + 512] = (v2 - mu) * rs * g[t + 512] + b[t + 512];
}

// ---------------------------------------------------------------------------
// fp32 GEMM: out[M,Nc] = act(A[M,K] @ W[K,Nc] + bias) (+ res)
// 128x128 tile, BK=16, 256 threads, 8x8 per-thread microtile.
// Nc and K are multiples of 128/16 for all call sites; only M has an edge.
// ---------------------------------------------------------------------------
#define LDS_STRIDE 132   // 128 + 4: float4-aligned, spreads store banks

__global__ __launch_bounds__(256) void gemm_kernel(
    const float* __restrict__ A, const float* __restrict__ W,
    const float* __restrict__ bias, const float* res, float* out,
    int M, int Nc, int K, int gelu_act)
{
    __shared__ float As[16][LDS_STRIDE];
    __shared__ float Bs[16][LDS_STRIDE];
    int t  = threadIdx.x;
    int tx = t & 15, ty = t >> 4;
    int m0 = blockIdx.y * 128, n0 = blockIdx.x * 128;

    float acc[8][8];
    #pragma unroll
    for (int i = 0; i < 8; i++)
        #pragma unroll
        for (int j = 0; j < 8; j++) acc[i][j] = 0.f;

    int ktiles = K >> 4;
    for (int kt = 0; kt < ktiles; ++kt) {
        int k0 = kt << 4;
        #pragma unroll
        for (int l = 0; l < 2; ++l) {
            int fid  = t + l * 256;
            // A tile: 128 rows x 16 cols, stored transposed As[k][m]
            int arow = fid >> 2;
            int ak4  = (fid & 3) << 2;
            float4 av = make_float4(0.f, 0.f, 0.f, 0.f);
            int gm = m0 + arow;
            if (gm < M) av = *(const float4*)(A + (size_t)gm * K + k0 + ak4);
            As[ak4 + 0][arow] = av.x;
            As[ak4 + 1][arow] = av.y;
            As[ak4 + 2][arow] = av.z;
            As[ak4 + 3][arow] = av.w;
            // B tile: 16 rows x 128 cols, natural layout
            int brow = fid >> 5;
            int bc   = (fid & 31) << 2;
            *(float4*)&Bs[brow][bc] =
                *(const float4*)(W + (size_t)(k0 + brow) * Nc + n0 + bc);
        }
        __syncthreads();
        #pragma unroll
        for (int kk = 0; kk < 16; ++kk) {
            float a[8], bv[8];
            *(float4*)&a[0]  = *(float4*)&As[kk][ty * 8];
            *(float4*)&a[4]  = *(float4*)&As[kk][ty * 8 + 4];
            *(float4*)&bv[0] = *(float4*)&Bs[kk][tx * 8];
            *(float4*)&bv[4] = *(float4*)&Bs[kk][tx * 8 + 4];
            #pragma unroll
            for (int i = 0; i < 8; i++)
                #pragma unroll
                for (int j = 0; j < 8; j++)
                    acc[i][j] = fmaf(a[i], bv[j], acc[i][j]);
        }
        __syncthreads();
    }

    #pragma unroll
    for (int i = 0; i < 8; i++) {
        int gm = m0 + ty * 8 + i;
        if (gm >= M) continue;
        #pragma unroll
        for (int j = 0; j < 8; j += 4) {
            int gn = n0 + tx * 8 + j;
            float4 v;
            v.x = acc[i][j + 0] + bias[gn + 0];
            v.y = acc[i][j + 1] + bias[gn + 1];
            v.z = acc[i][j + 2] + bias[gn + 2];
            v.w = acc[i][j + 3] + bias[gn + 3];
            if (gelu_act) {
                v.x = 0.5f * v.x * (1.f + erff(v.x * 0.70710678118654752f));
                v.y = 0.5f * v.y * (1.f + erff(v.y * 0.70710678118654752f));
                v.z = 0.5f * v.z * (1.f + erff(v.z * 0.70710678118654752f));
                v.w = 0.5f * v.w * (1.f + erff(v.w * 0.70710678118654752f));
            }
            if (res) {
                const float* rp = res + (size_t)gm * Nc + gn;
                v.x += rp[0]; v.y += rp[1]; v.z += rp[2]; v.w += rp[3];
            }
            *(float4*)(out + (size_t)gm * Nc + gn) = v;
        }
    }
}

// ---------------------------------------------------------------------------
// Fused attention, online softmax. Block = 256 thr (4 waves), handles one
// (b,h) and 16 q rows (4 per wave; lane owns output dim d=lane).
// qkv layout per row: [q(768) | k(768) | v(768)], head h at offset h*64.
// ---------------------------------------------------------------------------
__global__ __launch_bounds__(256) void attn_kernel(
    const float* __restrict__ qkv, float* __restrict__ outp)
{
    int bh = blockIdx.y;
    int b = bh / NH, h = bh % NH;
    int q0 = blockIdx.x * 16;
    int t = threadIdx.x;
    int lane = t & 63, w = t >> 6;

    __shared__ float q_s[16][64];
    __shared__ float Ks[64][65];   // +1 pad: 2-way bank alias = free
    __shared__ float Vs[64][65];
    __shared__ float p_s[16][64];

    {   // load 16 q rows (256 float4 = 16x64)
        int row = t >> 4;
        int d4  = (t & 15) << 2;
        float4 v = make_float4(0.f, 0.f, 0.f, 0.f);
        int gn = q0 + row;
        if (gn < NTOK)
            v = *(const float4*)(qkv + ((size_t)(b * NTOK + gn)) * 2304 + h * 64 + d4);
        *(float4*)&q_s[row][d4] = v;
    }
    float m_r[4], l_r[4], o_r[4];
    #pragma unroll
    for (int r = 0; r < 4; r++) { m_r[r] = -1e30f; l_r[r] = 0.f; o_r[r] = 0.f; }
    __syncthreads();

    for (int kt = 0; kt < 10; ++kt) {
        int j0 = kt * 64;
        #pragma unroll
        for (int l = 0; l < 4; ++l) {   // stage K,V tiles (64x64 each)
            int fid = t + l * 256;
            int jj  = fid >> 4;
            int d4  = (fid & 15) << 2;
            float4 kv = make_float4(0.f, 0.f, 0.f, 0.f);
            float4 vv = make_float4(0.f, 0.f, 0.f, 0.f);
            int gj = j0 + jj;
            if (gj < NTOK) {
                const float* base = qkv + ((size_t)(b * NTOK + gj)) * 2304 + h * 64 + d4;
                kv = *(const float4*)(base + 768);
                vv = *(const float4*)(base + 1536);
            }
            Ks[jj][d4 + 0] = kv.x; Ks[jj][d4 + 1] = kv.y;
            Ks[jj][d4 + 2] = kv.z; Ks[jj][d4 + 3] = kv.w;
            Vs[jj][d4 + 0] = vv.x; Vs[jj][d4 + 1] = vv.y;
            Vs[jj][d4 + 2] = vv.z; Vs[jj][d4 + 3] = vv.w;
        }
        __syncthreads();

        // QK^T: lane owns score column j=lane; 4 q rows at once
        float s4[4] = {0.f, 0.f, 0.f, 0.f};
        #pragma unroll 8
        for (int d = 0; d < 64; ++d) {
            float kval = Ks[lane][d];
            s4[0] = fmaf(q_s[w * 4 + 0][d], kval, s4[0]);
            s4[1] = fmaf(q_s[w * 4 + 1][d], kval, s4[1]);
            s4[2] = fmaf(q_s[w * 4 + 2][d], kval, s4[2]);
            s4[3] = fmaf(q_s[w * 4 + 3][d], kval, s4[3]);
        }
        bool valid = (j0 + lane) < NTOK;
        #pragma unroll
        for (int r = 0; r < 4; r++) {
            float s = valid ? s4[r] * 0.125f : -1e30f;
            float tmax = s;
            #pragma unroll
            for (int off = 32; off; off >>= 1) tmax = fmaxf(tmax, __shfl_xor(tmax, off));
            float m_new = fmaxf(m_r[r], tmax);
            float p     = __expf(s - m_new);
            float alpha = __expf(m_r[r] - m_new);
            float psum = p;
            #pragma unroll
            for (int off = 32; off; off >>= 1) psum += __shfl_xor(psum, off);
            l_r[r] = l_r[r] * alpha + psum;
            m_r[r] = m_new;
            p_s[w * 4 + r][lane] = p;   // wave-local LDS exchange (in-order DS)
            o_r[r] *= alpha;
        }
        // PV: lane owns output dim d=lane
        #pragma unroll 8
        for (int j = 0; j < 64; ++j) {
            float vval = Vs[j][lane];
            o_r[0] = fmaf(p_s[w * 4 + 0][j], vval, o_r[0]);
            o_r[1] = fmaf(p_s[w * 4 + 1][j], vval, o_r[1]);
            o_r[2] = fmaf(p_s[w * 4 + 2][j], vval, o_r[2]);
            o_r[3] = fmaf(p_s[w * 4 + 3][j], vval, o_r[3]);
        }
        __syncthreads();
    }
    #pragma unroll
    for (int r = 0; r < 4; r++) {
        int gn = q0 + w * 4 + r;
        if (gn < NTOK)
            outp[((size_t)(b * NTOK + gn)) * CDIM + h * 64 + lane] = o_r[r] / l_r[r];
    }
}

// ---------------------------------------------------------------------------
extern "C" void kernel_launch(void* const* d_in, const int* in_sizes, int n_in,
                              void* d_out, int out_size, void* d_ws, size_t ws_size,
                              hipStream_t stream)
{
    const float* x      = (const float*)d_in[0];
    const float* ln1_g  = (const float*)d_in[1];
    const float* ln1_b  = (const float*)d_in[2];
    const float* w_qkv  = (const float*)d_in[3];
    const float* b_qkv  = (const float*)d_in[4];
    const float* w_proj = (const float*)d_in[5];
    const float* b_proj = (const float*)d_in[6];
    const float* ln2_g  = (const float*)d_in[7];
    const float* ln2_b  = (const float*)d_in[8];
    const float* w_fc1  = (const float*)d_in[9];
    const float* b_fc1  = (const float*)d_in[10];
    const float* w_fc2  = (const float*)d_in[11];
    const float* b_fc2  = (const float*)d_in[12];
    float* out = (float*)d_out;

    float* ws  = (float*)d_ws;
    float* h    = ws;                            // RTOT*768   (h1 / attnout / h2)
    float* qkvb = h    + (size_t)RTOT * CDIM;    // RTOT*2304
    float* h3   = qkvb + (size_t)RTOT * 3 * CDIM;// RTOT*3072
    // x1 (residual after proj) lives in d_out and is overwritten by fc2.

    int mblocks = (RTOT + 127) / 128;            // 73

    // 1. h = LN1(x)
    ln_kernel<<<RTOT, 256, 0, stream>>>(x, ln1_g, ln1_b, h);
    // 2. qkv = h @ w_qkv + b_qkv
    gemm_kernel<<<dim3(3 * CDIM / 128, mblocks), 256, 0, stream>>>(
        h, w_qkv, b_qkv, nullptr, qkvb, RTOT, 3 * CDIM, CDIM, 0);
    // 3. attnout (reuse h) = softmax(q k^T / 8) v, heads merged
    attn_kernel<<<dim3((NTOK + 15) / 16, NB * NH), 256, 0, stream>>>(qkvb, h);
    // 4. x1 = x + attnout @ w_proj + b_proj   -> d_out
    gemm_kernel<<<dim3(CDIM / 128, mblocks), 256, 0, stream>>>(
        h, w_proj, b_proj, x, out, RTOT, CDIM, CDIM, 0);
    // 5. h = LN2(x1)
    ln_kernel<<<RTOT, 256, 0, stream>>>(out, ln2_g, ln2_b, h);
    // 6. h3 = gelu(h @ w_fc1 + b_fc1)
    gemm_kernel<<<dim3(HID / 128, mblocks), 256, 0, stream>>>(
        h, w_fc1, b_fc1, nullptr, h3, RTOT, HID, CDIM, 1);
    // 7. out = x1 + h3 @ w_fc2 + b_fc2   (res == out: same-element, same-thread)
    gemm_kernel<<<dim3(CDIM / 128, mblocks), 256, 0, stream>>>(
        h3, w_fc2, b_fc2, out, out, RTOT, CDIM, HID, 0);
}

// Round 2
// 1127.412 us; speedup vs baseline: 2.1227x; 2.1227x over previous
//
#include <hip/hip_runtime.h>
#include <hip/hip_bf16.h>
#include <math.h>

#define NB   16
#define NTOK 577
#define CDIM 768
#define NH   12
#define HID  3072
#define RTOT (NB*NTOK)        // 9232
#define MT   ((RTOT+127)/128) // 73 m-tiles
#define RPAD (MT*128)         // 9344 padded rows

typedef __attribute__((ext_vector_type(8))) short bf16x8;
typedef __attribute__((ext_vector_type(4))) float f32x4;

__device__ inline void load_lds16(const void* g, void* l) {
    __builtin_amdgcn_global_load_lds(
        (const __attribute__((address_space(1))) unsigned*)g,
        (__attribute__((address_space(3))) unsigned*)l, 16, 0, 0);
}

// ---------------------------------------------------------------------------
// Weight convert+transpose: src fp32 [K][N] -> dst bf16 [N][K]
// ---------------------------------------------------------------------------
__global__ __launch_bounds__(256) void wconvert(
    const float* __restrict__ src, __hip_bfloat16* __restrict__ dst,
    int K, int N)
{
    __shared__ float tile[64][65];
    int n0 = blockIdx.x * 64, k0 = blockIdx.y * 64;
    int c = threadIdx.x & 63, r = threadIdx.x >> 6;
    #pragma unroll 4
    for (int i = 0; i < 16; ++i)
        tile[r + i * 4][c] = src[(size_t)(k0 + r + i * 4) * N + n0 + c];
    __syncthreads();
    #pragma unroll 4
    for (int i = 0; i < 16; ++i)
        dst[(size_t)(n0 + r + i * 4) * K + k0 + c] =
            __float2bfloat16(tile[c][r + i * 4]);
}

// ---------------------------------------------------------------------------
// LayerNorm: one 256-thread block per row (768 elems); bf16 output
// ---------------------------------------------------------------------------
__global__ __launch_bounds__(256) void ln_kernel(
    const float* __restrict__ x, const float* __restrict__ g,
    const float* __restrict__ b, __hip_bfloat16* __restrict__ out)
{
    int row = blockIdx.x;
    const float* xr = x + (size_t)row * CDIM;
    __hip_bfloat16* orow = out + (size_t)row * CDIM;
    int t = threadIdx.x;
    float v0 = xr[t], v1 = xr[t + 256], v2 = xr[t + 512];
    float s  = v0 + v1 + v2;
    float s2 = v0*v0 + v1*v1 + v2*v2;
    #pragma unroll
    for (int off = 32; off; off >>= 1) {
        s  += __shfl_xor(s, off);
        s2 += __shfl_xor(s2, off);
    }
    __shared__ float red[10];
    int wave = t >> 6, lane = t & 63;
    if (lane == 0) { red[wave] = s; red[wave + 4] = s2; }
    __syncthreads();
    if (t == 0) {
        float ts  = red[0] + red[1] + red[2] + red[3];
        float ts2 = red[4] + red[5] + red[6] + red[7];
        float mu  = ts * (1.0f / CDIM);
        float var = ts2 * (1.0f / CDIM) - mu * mu;
        red[8] = mu;
        red[9] = rsqrtf(var + 1e-5f);
    }
    __syncthreads();
    float mu = red[8], rs = red[9];
    orow[t]       = __float2bfloat16((v0 - mu) * rs * g[t]       + b[t]);
    orow[t + 256] = __float2bfloat16((v1 - mu) * rs * g[t + 256] + b[t + 256]);
    orow[t + 512] = __float2bfloat16((v2 - mu) * rs * g[t + 512] + b[t + 512]);
}

// ---------------------------------------------------------------------------
// bf16 MFMA GEMM (m97 structure): out[M,Nc] = act(A[M,K] @ Bt[Nc,K]^T + bias)
// A bf16 [RPAD][K], Bt bf16 [Nc][K]. 128x128 tile, BK=32, 4 waves, each wave
// 4x4 tiles of 16x16x32. flags: bit0 = gelu, bit1 = bf16 output.
// res (fp32 [M][Nc]) optional. res==out aliasing is same-thread-safe.
// ---------------------------------------------------------------------------
__global__ __launch_bounds__(256) void mfma_gemm(
    const __hip_bfloat16* __restrict__ A,
    const __hip_bfloat16* __restrict__ Bt,
    const float* __restrict__ bias, const float* __restrict__ res,
    void* __restrict__ outv, int M, int Nc, int K, int flags)
{
    __shared__ __align__(16) __hip_bfloat16 As[128 * 32];
    __shared__ __align__(16) __hip_bfloat16 Bs[128 * 32];
    int t = threadIdx.x;
    int lane = t & 63, wv = t >> 6;
    int m0 = blockIdx.y * 128, n0 = blockIdx.x * 128;

    // staging: thread t loads 16B from row (t>>2)+64l, k-chunk (t&3)*8
    const __hip_bfloat16* Ag = A  + (size_t)(m0 + (t >> 2)) * K + (t & 3) * 8;
    const __hip_bfloat16* Bg = Bt + (size_t)(n0 + (t >> 2)) * K + (t & 3) * 8;
    __hip_bfloat16* lAs = As + wv * 512;   // wave-uniform LDS dest base
    __hip_bfloat16* lBs = Bs + wv * 512;

    int fr = lane & 15, fq = lane >> 4;
    int wm = (wv >> 1) * 64, wn = (wv & 1) * 64;
    const __hip_bfloat16* pa = As + (wm + fr) * 32 + fq * 8;
    const __hip_bfloat16* pb = Bs + (wn + fr) * 32 + fq * 8;

    f32x4 acc[4][4];
    #pragma unroll
    for (int i = 0; i < 4; ++i)
        #pragma unroll
        for (int j = 0; j < 4; ++j) acc[i][j] = (f32x4){0.f, 0.f, 0.f, 0.f};

    int ktiles = K >> 5;
    for (int k = 0; k < ktiles; ++k) {
        load_lds16(Ag,          lAs);
        load_lds16(Ag + 64 * K, lAs + 2048);
        load_lds16(Bg,          lBs);
        load_lds16(Bg + 64 * K, lBs + 2048);
        Ag += 32; Bg += 32;
        __syncthreads();
        bf16x8 af[4], bf[4];
        #pragma unroll
        for (int tm = 0; tm < 4; ++tm)
            af[tm] = *(const bf16x8*)(pa + tm * 16 * 32);
        #pragma unroll
        for (int tn = 0; tn < 4; ++tn)
            bf[tn] = *(const bf16x8*)(pb + tn * 16 * 32);
        #pragma unroll
        for (int tm = 0; tm < 4; ++tm)
            #pragma unroll
            for (int tn = 0; tn < 4; ++tn)
                acc[tm][tn] = __builtin_amdgcn_mfma_f32_16x16x32_bf16(
                    af[tm], bf[tn], acc[tm][tn], 0, 0, 0);
        __syncthreads();
    }

    float* outf = (float*)outv;
    __hip_bfloat16* outb = (__hip_bfloat16*)outv;
    int gelu = flags & 1, obf = flags & 2;
    #pragma unroll
    for (int tm = 0; tm < 4; ++tm) {
        #pragma unroll
        for (int rg = 0; rg < 4; ++rg) {
            int gm = m0 + wm + tm * 16 + fq * 4 + rg;
            if (gm >= M) continue;
            #pragma unroll
            for (int tn = 0; tn < 4; ++tn) {
                int gn = n0 + wn + tn * 16 + fr;
                float v = acc[tm][tn][rg] + bias[gn];
                if (gelu) v = 0.5f * v * (1.f + erff(v * 0.70710678118654752f));
                if (res)  v += res[(size_t)gm * Nc + gn];
                if (obf) outb[(size_t)gm * Nc + gn] = __float2bfloat16(v);
                else     outf[(size_t)gm * Nc + gn] = v;
            }
        }
    }
}

// ---------------------------------------------------------------------------
// Fused attention (unchanged from R1 except bf16 output store).
// qkv fp32 per row: [q(768) | k(768) | v(768)], head h at offset h*64.
// ---------------------------------------------------------------------------
__global__ __launch_bounds__(256) void attn_kernel(
    const float* __restrict__ qkv, __hip_bfloat16* __restrict__ outp)
{
    int bh = blockIdx.y;
    int b = bh / NH, h = bh % NH;
    int q0 = blockIdx.x * 16;
    int t = threadIdx.x;
    int lane = t & 63, w = t >> 6;

    __shared__ float q_s[16][64];
    __shared__ float Ks[64][65];
    __shared__ float Vs[64][65];
    __shared__ float p_s[16][64];

    {
        int row = t >> 4;
        int d4  = (t & 15) << 2;
        float4 v = make_float4(0.f, 0.f, 0.f, 0.f);
        int gn = q0 + row;
        if (gn < NTOK)
            v = *(const float4*)(qkv + ((size_t)(b * NTOK + gn)) * 2304 + h * 64 + d4);
        *(float4*)&q_s[row][d4] = v;
    }
    float m_r[4], l_r[4], o_r[4];
    #pragma unroll
    for (int r = 0; r < 4; r++) { m_r[r] = -1e30f; l_r[r] = 0.f; o_r[r] = 0.f; }
    __syncthreads();

    for (int kt = 0; kt < 10; ++kt) {
        int j0 = kt * 64;
        #pragma unroll
        for (int l = 0; l < 4; ++l) {
            int fid = t + l * 256;
            int jj  = fid >> 4;
            int d4  = (fid & 15) << 2;
            float4 kv = make_float4(0.f, 0.f, 0.f, 0.f);
            float4 vv = make_float4(0.f, 0.f, 0.f, 0.f);
            int gj = j0 + jj;
            if (gj < NTOK) {
                const float* base = qkv + ((size_t)(b * NTOK + gj)) * 2304 + h * 64 + d4;
                kv = *(const float4*)(base + 768);
                vv = *(const float4*)(base + 1536);
            }
            Ks[jj][d4 + 0] = kv.x; Ks[jj][d4 + 1] = kv.y;
            Ks[jj][d4 + 2] = kv.z; Ks[jj][d4 + 3] = kv.w;
            Vs[jj][d4 + 0] = vv.x; Vs[jj][d4 + 1] = vv.y;
            Vs[jj][d4 + 2] = vv.z; Vs[jj][d4 + 3] = vv.w;
        }
        __syncthreads();

        float s4[4] = {0.f, 0.f, 0.f, 0.f};
        #pragma unroll 8
        for (int d = 0; d < 64; ++d) {
            float kval = Ks[lane][d];
            s4[0] = fmaf(q_s[w * 4 + 0][d], kval, s4[0]);
            s4[1] = fmaf(q_s[w * 4 + 1][d], kval, s4[1]);
            s4[2] = fmaf(q_s[w * 4 + 2][d], kval, s4[2]);
            s4[3] = fmaf(q_s[w * 4 + 3][d], kval, s4[3]);
        }
        bool valid = (j0 + lane) < NTOK;
        #pragma unroll
        for (int r = 0; r < 4; r++) {
            float s = valid ? s4[r] * 0.125f : -1e30f;
            float tmax = s;
            #pragma unroll
            for (int off = 32; off; off >>= 1) tmax = fmaxf(tmax, __shfl_xor(tmax, off));
            float m_new = fmaxf(m_r[r], tmax);
            float p     = __expf(s - m_new);
            float alpha = __expf(m_r[r] - m_new);
            float psum = p;
            #pragma unroll
            for (int off = 32; off; off >>= 1) psum += __shfl_xor(psum, off);
            l_r[r] = l_r[r] * alpha + psum;
            m_r[r] = m_new;
            p_s[w * 4 + r][lane] = p;
            o_r[r] *= alpha;
        }
        #pragma unroll 8
        for (int j = 0; j < 64; ++j) {
            float vval = Vs[j][lane];
            o_r[0] = fmaf(p_s[w * 4 + 0][j], vval, o_r[0]);
            o_r[1] = fmaf(p_s[w * 4 + 1][j], vval, o_r[1]);
            o_r[2] = fmaf(p_s[w * 4 + 2][j], vval, o_r[2]);
            o_r[3] = fmaf(p_s[w * 4 + 3][j], vval, o_r[3]);
        }
        __syncthreads();
    }
    #pragma unroll
    for (int r = 0; r < 4; r++) {
        int gn = q0 + w * 4 + r;
        if (gn < NTOK)
            outp[((size_t)(b * NTOK + gn)) * CDIM + h * 64 + lane] =
                __float2bfloat16(o_r[r] / l_r[r]);
    }
}

// ---------------------------------------------------------------------------
extern "C" void kernel_launch(void* const* d_in, const int* in_sizes, int n_in,
                              void* d_out, int out_size, void* d_ws, size_t ws_size,
                              hipStream_t stream)
{
    const float* x      = (const float*)d_in[0];
    const float* ln1_g  = (const float*)d_in[1];
    const float* ln1_b  = (const float*)d_in[2];
    const float* w_qkv  = (const float*)d_in[3];
    const float* b_qkv  = (const float*)d_in[4];
    const float* w_proj = (const float*)d_in[5];
    const float* b_proj = (const float*)d_in[6];
    const float* ln2_g  = (const float*)d_in[7];
    const float* ln2_b  = (const float*)d_in[8];
    const float* w_fc1  = (const float*)d_in[9];
    const float* b_fc1  = (const float*)d_in[10];
    const float* w_fc2  = (const float*)d_in[11];
    const float* b_fc2  = (const float*)d_in[12];
    float* out = (float*)d_out;

    char* w = (char*)d_ws;
    __hip_bfloat16* wqkv_t = (__hip_bfloat16*)w; w += (size_t)3*CDIM*CDIM*2;
    __hip_bfloat16* wproj_t= (__hip_bfloat16*)w; w += (size_t)CDIM*CDIM*2;
    __hip_bfloat16* wfc1_t = (__hip_bfloat16*)w; w += (size_t)HID*CDIM*2;
    __hip_bfloat16* wfc2_t = (__hip_bfloat16*)w; w += (size_t)CDIM*HID*2;
    __hip_bfloat16* h_bf   = (__hip_bfloat16*)w; w += (size_t)RPAD*CDIM*2;
    __hip_bfloat16* h3_bf  = (__hip_bfloat16*)w; w += (size_t)RPAD*HID*2;
    float*          qkvb   = (float*)w;          // RTOT*2304 fp32

    // 0. weights -> bf16, transposed [N][K]
    wconvert<<<dim3(3*CDIM/64, CDIM/64), 256, 0, stream>>>(w_qkv,  wqkv_t, CDIM, 3*CDIM);
    wconvert<<<dim3(CDIM/64,   CDIM/64), 256, 0, stream>>>(w_proj, wproj_t, CDIM, CDIM);
    wconvert<<<dim3(HID/64,    CDIM/64), 256, 0, stream>>>(w_fc1,  wfc1_t, CDIM, HID);
    wconvert<<<dim3(CDIM/64,   HID/64),  256, 0, stream>>>(w_fc2,  wfc2_t, HID, CDIM);

    // 1. h = LN1(x)   (bf16)
    ln_kernel<<<RTOT, 256, 0, stream>>>(x, ln1_g, ln1_b, h_bf);
    // 2. qkv = h @ w_qkv + b_qkv   (fp32 out)
    mfma_gemm<<<dim3(3*CDIM/128, MT), 256, 0, stream>>>(
        h_bf, wqkv_t, b_qkv, nullptr, qkvb, RTOT, 3*CDIM, CDIM, 0);
    // 3. attnout = softmax(q k^T/8) v  -> h_bf (bf16)
    attn_kernel<<<dim3((NTOK + 15)/16, NB*NH), 256, 0, stream>>>(qkvb, h_bf);
    // 4. x1 = x + attnout @ w_proj + b_proj  -> d_out (fp32)
    mfma_gemm<<<dim3(CDIM/128, MT), 256, 0, stream>>>(
        h_bf, wproj_t, b_proj, x, out, RTOT, CDIM, CDIM, 0);
    // 5. h = LN2(x1)  (bf16)
    ln_kernel<<<RTOT, 256, 0, stream>>>(out, ln2_g, ln2_b, h_bf);
    // 6. h3 = gelu(h @ w_fc1 + b_fc1)  (bf16 out)
    mfma_gemm<<<dim3(HID/128, MT), 256, 0, stream>>>(
        h_bf, wfc1_t, b_fc1, nullptr, h3_bf, RTOT, HID, CDIM, 1 | 2);
    // 7. out = x1 + h3 @ w_fc2 + b_fc2  (fp32, res==out same-thread)
    mfma_gemm<<<dim3(CDIM/128, MT), 256, 0, stream>>>(
        h3_bf, wfc2_t, b_fc2, out, out, RTOT, CDIM, HID, 0);
}

// Round 3
// 583.451 us; speedup vs baseline: 4.1017x; 1.9323x over previous
//
#include <hip/hip_runtime.h>
#include <hip/hip_bf16.h>
#include <math.h>

#define NB   16
#define NTOK 577
#define CDIM 768
#define NH   12
#define HID  3072
#define RTOT (NB*NTOK)        // 9232
#define MT   ((RTOT+127)/128) // 73
#define RPAD (MT*128)         // 9344
#define BH   (NB*NH)          // 192
#define QT   40               // 640/16 fragment-tiles per (b,h)

typedef __attribute__((ext_vector_type(8))) short bf16x8;
typedef __attribute__((ext_vector_type(4))) float f32x4;
typedef unsigned short u16;

__device__ inline void load_lds16(const void* g, void* l) {
    __builtin_amdgcn_global_load_lds(
        (const __attribute__((address_space(1))) unsigned*)g,
        (__attribute__((address_space(3))) unsigned*)l, 16, 0, 0);
}

// ---------------------------------------------------------------------------
// Weight convert+transpose: src fp32 [K][N] -> dst bf16 [N][K]
// ---------------------------------------------------------------------------
__global__ __launch_bounds__(256) void wconvert(
    const float* __restrict__ src, __hip_bfloat16* __restrict__ dst,
    int K, int N)
{
    __shared__ float tile[64][65];
    int n0 = blockIdx.x * 64, k0 = blockIdx.y * 64;
    int c = threadIdx.x & 63, r = threadIdx.x >> 6;
    #pragma unroll 4
    for (int i = 0; i < 16; ++i)
        tile[r + i * 4][c] = src[(size_t)(k0 + r + i * 4) * N + n0 + c];
    __syncthreads();
    #pragma unroll 4
    for (int i = 0; i < 16; ++i)
        dst[(size_t)(n0 + r + i * 4) * K + k0 + c] =
            __float2bfloat16(tile[c][r + i * 4]);
}

// ---------------------------------------------------------------------------
// LayerNorm -> bf16
// ---------------------------------------------------------------------------
__global__ __launch_bounds__(256) void ln_kernel(
    const float* __restrict__ x, const float* __restrict__ g,
    const float* __restrict__ b, __hip_bfloat16* __restrict__ out)
{
    int row = blockIdx.x;
    const float* xr = x + (size_t)row * CDIM;
    __hip_bfloat16* orow = out + (size_t)row * CDIM;
    int t = threadIdx.x;
    float v0 = xr[t], v1 = xr[t + 256], v2 = xr[t + 512];
    float s  = v0 + v1 + v2;
    float s2 = v0*v0 + v1*v1 + v2*v2;
    #pragma unroll
    for (int off = 32; off; off >>= 1) {
        s  += __shfl_xor(s, off);
        s2 += __shfl_xor(s2, off);
    }
    __shared__ float red[10];
    int wave = t >> 6, lane = t & 63;
    if (lane == 0) { red[wave] = s; red[wave + 4] = s2; }
    __syncthreads();
    if (t == 0) {
        float ts  = red[0] + red[1] + red[2] + red[3];
        float ts2 = red[4] + red[5] + red[6] + red[7];
        float mu  = ts * (1.0f / CDIM);
        float var = ts2 * (1.0f / CDIM) - mu * mu;
        red[8] = mu;
        red[9] = rsqrtf(var + 1e-5f);
    }
    __syncthreads();
    float mu = red[8], rs = red[9];
    orow[t]       = __float2bfloat16((v0 - mu) * rs * g[t]       + b[t]);
    orow[t + 256] = __float2bfloat16((v1 - mu) * rs * g[t + 256] + b[t + 256]);
    orow[t + 512] = __float2bfloat16((v2 - mu) * rs * g[t + 512] + b[t + 512]);
}

// ---------------------------------------------------------------------------
// bf16 MFMA GEMM (m97 structure). flags: bit0=gelu, bit1=bf16 out.
// ---------------------------------------------------------------------------
__global__ __launch_bounds__(256) void mfma_gemm(
    const __hip_bfloat16* __restrict__ A,
    const __hip_bfloat16* __restrict__ Bt,
    const float* __restrict__ bias, const float* __restrict__ res,
    void* __restrict__ outv, int M, int Nc, int K, int flags)
{
    __shared__ __align__(16) __hip_bfloat16 As[128 * 32];
    __shared__ __align__(16) __hip_bfloat16 Bs[128 * 32];
    int t = threadIdx.x;
    int lane = t & 63, wv = t >> 6;
    int m0 = blockIdx.y * 128, n0 = blockIdx.x * 128;

    const __hip_bfloat16* Ag = A  + (size_t)(m0 + (t >> 2)) * K + (t & 3) * 8;
    const __hip_bfloat16* Bg = Bt + (size_t)(n0 + (t >> 2)) * K + (t & 3) * 8;
    __hip_bfloat16* lAs = As + wv * 512;
    __hip_bfloat16* lBs = Bs + wv * 512;

    int fr = lane & 15, fq = lane >> 4;
    int wm = (wv >> 1) * 64, wn = (wv & 1) * 64;
    const __hip_bfloat16* pa = As + (wm + fr) * 32 + fq * 8;
    const __hip_bfloat16* pb = Bs + (wn + fr) * 32 + fq * 8;

    f32x4 acc[4][4];
    #pragma unroll
    for (int i = 0; i < 4; ++i)
        #pragma unroll
        for (int j = 0; j < 4; ++j) acc[i][j] = (f32x4){0.f, 0.f, 0.f, 0.f};

    int ktiles = K >> 5;
    for (int k = 0; k < ktiles; ++k) {
        load_lds16(Ag,          lAs);
        load_lds16(Ag + 64 * K, lAs + 2048);
        load_lds16(Bg,          lBs);
        load_lds16(Bg + 64 * K, lBs + 2048);
        Ag += 32; Bg += 32;
        __syncthreads();
        bf16x8 af[4], bf[4];
        #pragma unroll
        for (int tm = 0; tm < 4; ++tm)
            af[tm] = *(const bf16x8*)(pa + tm * 16 * 32);
        #pragma unroll
        for (int tn = 0; tn < 4; ++tn)
            bf[tn] = *(const bf16x8*)(pb + tn * 16 * 32);
        #pragma unroll
        for (int tm = 0; tm < 4; ++tm)
            #pragma unroll
            for (int tn = 0; tn < 4; ++tn)
                acc[tm][tn] = __builtin_amdgcn_mfma_f32_16x16x32_bf16(
                    af[tm], bf[tn], acc[tm][tn], 0, 0, 0);
        __syncthreads();
    }

    float* outf = (float*)outv;
    __hip_bfloat16* outb = (__hip_bfloat16*)outv;
    int gelu = flags & 1, obf = flags & 2;
    #pragma unroll
    for (int tm = 0; tm < 4; ++tm) {
        #pragma unroll
        for (int rg = 0; rg < 4; ++rg) {
            int gm = m0 + wm + tm * 16 + fq * 4 + rg;
            if (gm >= M) continue;
            #pragma unroll
            for (int tn = 0; tn < 4; ++tn) {
                int gn = n0 + wn + tn * 16 + fr;
                float v = acc[tm][tn][rg] + bias[gn];
                if (gelu) v = 0.5f * v * (1.f + erff(v * 0.70710678118654752f));
                if (res)  v += res[(size_t)gm * Nc + gn];
                if (obf) outb[(size_t)gm * Nc + gn] = __float2bfloat16(v);
                else     outf[(size_t)gm * Nc + gn] = v;
            }
        }
    }
}

// ---------------------------------------------------------------------------
// Repack qkv (bf16 [RTOT][2304]) into fragment-ordered blobs.
// Q/K blob(bh, mt, kf): lane(fr,fq) = X[bh][mt*16+fr][kf*32+fq*8+jj], jj=0..7
// grid (QT, BH, 2): z=0 -> Q, z=1 -> K. Pad rows zero-filled.
// ---------------------------------------------------------------------------
__global__ __launch_bounds__(256) void repack_qk(
    const u16* __restrict__ qkv, u16* __restrict__ Qp, u16* __restrict__ Kp)
{
    __shared__ u16 blob[1024];
    int mt = blockIdx.x, bh = blockIdx.y, sec = blockIdx.z;
    int b = bh / NH, h = bh % NH;
    int t = threadIdx.x;
    int r = t >> 4, d = (t & 15) * 4;
    int row = mt * 16 + r;
    ushort4 v = make_ushort4(0, 0, 0, 0);
    if (row < NTOK)
        v = *(const ushort4*)(qkv + (size_t)(b * NTOK + row) * 2304 + sec * 768 + h * 64 + d);
    int kf = d >> 5, fq = (d >> 3) & 3, jj = d & 7;
    u16* p = blob + kf * 512 + (fq * 16 + r) * 8 + jj;
    p[0] = v.x; p[1] = v.y; p[2] = v.z; p[3] = v.w;
    __syncthreads();
    u16* dst = (sec == 0 ? Qp : Kp) + (size_t)(bh * QT + mt) * 1024;
    *(ushort4*)(dst + t * 4) = *(const ushort4*)(blob + t * 4);
}

// ---------------------------------------------------------------------------
// Repack V transposed: blob(bh, dt, jf): lane(fr,fq) = V[bh][jf*32+fq*8+jj][dt*16+fr]
// Vp layout [bh][dt(4)][jf(20)][512]. grid (10, BH).
// ---------------------------------------------------------------------------
__global__ __launch_bounds__(256) void repack_v(
    const u16* __restrict__ qkv, u16* __restrict__ Vp)
{
    __shared__ u16 blob[4096];   // [dt][jf_local][512]
    int jt = blockIdx.x, bh = blockIdx.y;
    int b = bh / NH, h = bh % NH;
    int t = threadIdx.x;
    int d = (t & 15) * 4;
    int dt = d >> 4;
    #pragma unroll
    for (int it = 0; it < 4; ++it) {
        int jr = (t >> 4) + it * 16;           // 0..63
        int row = jt * 64 + jr;
        ushort4 v = make_ushort4(0, 0, 0, 0);
        if (row < NTOK)
            v = *(const ushort4*)(qkv + (size_t)(b * NTOK + row) * 2304 + 1536 + h * 64 + d);
        int jf = jr >> 5, fq = (jr >> 3) & 3, jj = jr & 7;
        u16* p = blob + (dt * 2 + jf) * 512 + (fq * 16 + (d & 15)) * 8 + jj;
        p[0] = v.x; p[8] = v.y; p[16] = v.z; p[24] = v.w;
    }
    __syncthreads();
    #pragma unroll
    for (int dd = 0; dd < 4; ++dd) {
        size_t dstoff = ((size_t)(bh * 4 + dd) * 20 + jt * 2) * 512;
        *(ushort4*)(Vp + dstoff + t * 4) = *(const ushort4*)(blob + dd * 1024 + t * 4);
    }
}

// ---------------------------------------------------------------------------
// MFMA flash attention. Block = one (b,h) x 64 q rows; 4 waves x 16 rows.
// KV tiles of 64. All operands pre-packed in fragment order.
// ---------------------------------------------------------------------------
__global__ __launch_bounds__(256) void attn_mfma(
    const u16* __restrict__ Qp, const u16* __restrict__ Kp,
    const u16* __restrict__ Vp, __hip_bfloat16* __restrict__ outp)
{
    __shared__ __align__(16) u16 Ks[4096];          // [nt(4)][kf(2)][512]
    __shared__ __align__(16) u16 Vs[4096];          // [dt(4)][kfv(2)][512]
    __shared__ __align__(16) u16 Ps[4 * 16 * 72];   // per-wave 16 rows, stride 72

    int bh = blockIdx.y, qc = blockIdx.x;
    int b = bh / NH, h = bh % NH;
    int t = threadIdx.x, lane = t & 63, wv = t >> 6;
    int fr = lane & 15, fq = lane >> 4;

    int mt = qc * 4 + wv;
    const u16* qbase = Qp + (size_t)(bh * QT + mt) * 1024 + lane * 8;
    bf16x8 qf0 = *(const bf16x8*)(qbase);
    bf16x8 qf1 = *(const bf16x8*)(qbase + 512);

    const u16* kg = Kp + (size_t)bh * (QT * 1024) + wv * 1024 + lane * 8;
    const u16* vg = Vp + ((size_t)(bh * 4 + wv) * 20) * 512 + lane * 8;
    u16* lK  = Ks + wv * 1024;
    u16* lV  = Vs + wv * 1024;
    u16* psw = Ps + wv * (16 * 72);

    f32x4 o[4];
    float m_r[4], l_r[4];
    #pragma unroll
    for (int i = 0; i < 4; ++i) {
        o[i] = (f32x4){0.f, 0.f, 0.f, 0.f};
        m_r[i] = -1e30f; l_r[i] = 0.f;
    }

    for (int kt = 0; kt < 10; ++kt) {
        load_lds16(kg + kt * 4096,       lK);
        load_lds16(kg + kt * 4096 + 512, lK + 512);
        load_lds16(vg + kt * 1024,       lV);
        load_lds16(vg + kt * 1024 + 512, lV + 512);
        __syncthreads();

        // ---- S = Q @ K^T ----
        f32x4 sc[4];
        #pragma unroll
        for (int nt = 0; nt < 4; ++nt) {
            sc[nt] = (f32x4){0.f, 0.f, 0.f, 0.f};
            bf16x8 kf0 = *(const bf16x8*)(Ks + (nt * 2 + 0) * 512 + lane * 8);
            bf16x8 kf1 = *(const bf16x8*)(Ks + (nt * 2 + 1) * 512 + lane * 8);
            sc[nt] = __builtin_amdgcn_mfma_f32_16x16x32_bf16(qf0, kf0, sc[nt], 0, 0, 0);
            sc[nt] = __builtin_amdgcn_mfma_f32_16x16x32_bf16(qf1, kf1, sc[nt], 0, 0, 0);
        }

        // ---- online softmax (rows m = fq*4+rg, col j = j0 + nt*16 + fr) ----
        int j0 = kt * 64;
        float p[4][4], rm[4];
        #pragma unroll
        for (int rg = 0; rg < 4; ++rg) rm[rg] = -1e30f;
        #pragma unroll
        for (int nt = 0; nt < 4; ++nt) {
            bool valid = (j0 + nt * 16 + fr) < NTOK;
            #pragma unroll
            for (int rg = 0; rg < 4; ++rg) {
                float sv = valid ? sc[nt][rg] * 0.125f : -1e30f;
                p[nt][rg] = sv;
                rm[rg] = fmaxf(rm[rg], sv);
            }
        }
        #pragma unroll
        for (int rg = 0; rg < 4; ++rg) {
            #pragma unroll
            for (int off = 1; off < 16; off <<= 1)
                rm[rg] = fmaxf(rm[rg], __shfl_xor(rm[rg], off));
        }
        float alpha[4], rs[4];
        #pragma unroll
        for (int rg = 0; rg < 4; ++rg) {
            float mn = fmaxf(m_r[rg], rm[rg]);
            alpha[rg] = __expf(m_r[rg] - mn);
            m_r[rg] = mn;
            rs[rg] = 0.f;
        }
        #pragma unroll
        for (int nt = 0; nt < 4; ++nt)
            #pragma unroll
            for (int rg = 0; rg < 4; ++rg) {
                float pv = __expf(p[nt][rg] - m_r[rg]);
                p[nt][rg] = pv;
                rs[rg] += pv;
            }
        #pragma unroll
        for (int rg = 0; rg < 4; ++rg) {
            #pragma unroll
            for (int off = 1; off < 16; off <<= 1)
                rs[rg] += __shfl_xor(rs[rg], off);
            l_r[rg] = l_r[rg] * alpha[rg] + rs[rg];
        }

        // ---- P -> LDS (wave-private), rescale O ----
        #pragma unroll
        for (int nt = 0; nt < 4; ++nt)
            #pragma unroll
            for (int rg = 0; rg < 4; ++rg) {
                __hip_bfloat16 hb = __float2bfloat16(p[nt][rg]);
                psw[(fq * 4 + rg) * 72 + nt * 16 + fr] = *(u16*)&hb;
            }
        #pragma unroll
        for (int dt = 0; dt < 4; ++dt)
            #pragma unroll
            for (int rg = 0; rg < 4; ++rg)
                o[dt][rg] *= alpha[rg];

        // ---- O += P @ V ----
        bf16x8 pf0 = *(const bf16x8*)(psw + fr * 72 + fq * 8);
        bf16x8 pf1 = *(const bf16x8*)(psw + fr * 72 + 32 + fq * 8);
        #pragma unroll
        for (int dt = 0; dt < 4; ++dt) {
            bf16x8 bv0 = *(const bf16x8*)(Vs + (dt * 2 + 0) * 512 + lane * 8);
            bf16x8 bv1 = *(const bf16x8*)(Vs + (dt * 2 + 1) * 512 + lane * 8);
            o[dt] = __builtin_amdgcn_mfma_f32_16x16x32_bf16(pf0, bv0, o[dt], 0, 0, 0);
            o[dt] = __builtin_amdgcn_mfma_f32_16x16x32_bf16(pf1, bv1, o[dt], 0, 0, 0);
        }
        __syncthreads();
    }

    #pragma unroll
    for (int rg = 0; rg < 4; ++rg) {
        int row = qc * 64 + wv * 16 + fq * 4 + rg;
        if (row < NTOK) {
            float rl = 1.0f / l_r[rg];
            #pragma unroll
            for (int dt = 0; dt < 4; ++dt)
                outp[(size_t)(b * NTOK + row) * CDIM + h * 64 + dt * 16 + fr] =
                    __float2bfloat16(o[dt][rg] * rl);
        }
    }
}

// ---------------------------------------------------------------------------
extern "C" void kernel_launch(void* const* d_in, const int* in_sizes, int n_in,
                              void* d_out, int out_size, void* d_ws, size_t ws_size,
                              hipStream_t stream)
{
    const float* x      = (const float*)d_in[0];
    const float* ln1_g  = (const float*)d_in[1];
    const float* ln1_b  = (const float*)d_in[2];
    const float* w_qkv  = (const float*)d_in[3];
    const float* b_qkv  = (const float*)d_in[4];
    const float* w_proj = (const float*)d_in[5];
    const float* b_proj = (const float*)d_in[6];
    const float* ln2_g  = (const float*)d_in[7];
    const float* ln2_b  = (const float*)d_in[8];
    const float* w_fc1  = (const float*)d_in[9];
    const float* b_fc1  = (const float*)d_in[10];
    const float* w_fc2  = (const float*)d_in[11];
    const float* b_fc2  = (const float*)d_in[12];
    float* out = (float*)d_out;

    char* w = (char*)d_ws;
    __hip_bfloat16* wqkv_t = (__hip_bfloat16*)w; w += (size_t)3*CDIM*CDIM*2;
    __hip_bfloat16* wproj_t= (__hip_bfloat16*)w; w += (size_t)CDIM*CDIM*2;
    __hip_bfloat16* wfc1_t = (__hip_bfloat16*)w; w += (size_t)HID*CDIM*2;
    __hip_bfloat16* wfc2_t = (__hip_bfloat16*)w; w += (size_t)CDIM*HID*2;
    __hip_bfloat16* h_bf   = (__hip_bfloat16*)w; w += (size_t)RPAD*CDIM*2;
    __hip_bfloat16* h3_bf  = (__hip_bfloat16*)w; w += (size_t)RPAD*HID*2;
    u16*            qkv_bf = (u16*)w;            w += (size_t)RTOT*3*CDIM*2;
    u16*            Qp     = (u16*)w;            w += (size_t)BH*QT*1024*2;
    u16*            Kp     = (u16*)w;            w += (size_t)BH*QT*1024*2;
    u16*            Vp     = (u16*)w;            w += (size_t)BH*4*20*512*2;

    // 0. weights -> bf16 transposed [N][K]
    wconvert<<<dim3(3*CDIM/64, CDIM/64), 256, 0, stream>>>(w_qkv,  wqkv_t, CDIM, 3*CDIM);
    wconvert<<<dim3(CDIM/64,   CDIM/64), 256, 0, stream>>>(w_proj, wproj_t, CDIM, CDIM);
    wconvert<<<dim3(HID/64,    CDIM/64), 256, 0, stream>>>(w_fc1,  wfc1_t, CDIM, HID);
    wconvert<<<dim3(CDIM/64,   HID/64),  256, 0, stream>>>(w_fc2,  wfc2_t, HID, CDIM);

    // 1. h = LN1(x)
    ln_kernel<<<RTOT, 256, 0, stream>>>(x, ln1_g, ln1_b, h_bf);
    // 2. qkv = h @ w_qkv + b_qkv  (bf16 out)
    mfma_gemm<<<dim3(3*CDIM/128, MT), 256, 0, stream>>>(
        h_bf, wqkv_t, b_qkv, nullptr, qkv_bf, RTOT, 3*CDIM, CDIM, 2);
    // 3. fragment-pack q/k/v
    repack_qk<<<dim3(QT, BH, 2), 256, 0, stream>>>(qkv_bf, Qp, Kp);
    repack_v <<<dim3(10, BH),    256, 0, stream>>>(qkv_bf, Vp);
    // 4. attention -> h_bf
    attn_mfma<<<dim3(10, BH), 256, 0, stream>>>(Qp, Kp, Vp, h_bf);
    // 5. x1 = x + attnout @ w_proj + b_proj -> d_out (fp32)
    mfma_gemm<<<dim3(CDIM/128, MT), 256, 0, stream>>>(
        h_bf, wproj_t, b_proj, x, out, RTOT, CDIM, CDIM, 0);
    // 6. h = LN2(x1)
    ln_kernel<<<RTOT, 256, 0, stream>>>(out, ln2_g, ln2_b, h_bf);
    // 7. h3 = gelu(h @ w_fc1 + b_fc1)  (bf16 out)
    mfma_gemm<<<dim3(HID/128, MT), 256, 0, stream>>>(
        h_bf, wfc1_t, b_fc1, nullptr, h3_bf, RTOT, HID, CDIM, 1 | 2);
    // 8. out = x1 + h3 @ w_fc2 + b_fc2  (fp32, res==out same-thread)
    mfma_gemm<<<dim3(CDIM/128, MT), 256, 0, stream>>>(
        h3_bf, wfc2_t, b_fc2, out, out, RTOT, CDIM, HID, 0);
}

// Round 4
// 554.741 us; speedup vs baseline: 4.3140x; 1.0518x over previous
//
#include <hip/hip_runtime.h>
#include <hip/hip_bf16.h>
#include <math.h>

#define NB   16
#define NTOK 577
#define CDIM 768
#define NH   12
#define HID  3072
#define RTOT (NB*NTOK)        // 9232
#define MT   ((RTOT+127)/128) // 73
#define RPAD (MT*128)         // 9344
#define BH   (NB*NH)          // 192
#define QT   40               // 640/16 fragment-tiles per (b,h)

typedef __attribute__((ext_vector_type(8))) short bf16x8;
typedef __attribute__((ext_vector_type(4))) float f32x4;
typedef unsigned short u16;

__device__ inline void load_lds16(const void* g, void* l) {
    __builtin_amdgcn_global_load_lds(
        (const __attribute__((address_space(1))) unsigned*)g,
        (__attribute__((address_space(3))) unsigned*)l, 16, 0, 0);
}

// exp-based tanh gelu: one v_exp_f32 + one rcp; saturates cleanly (no NaN).
__device__ inline float fast_gelu(float x) {
    float y = 0.7978845608f * (x + 0.044715f * x * x * x);
    float e = __expf(2.0f * y);
    float th = 1.0f - 2.0f / (e + 1.0f);
    return 0.5f * x * (1.0f + th);
}

// ---------------------------------------------------------------------------
// Weight convert+transpose: src fp32 [K][N] -> dst bf16 [N][K]
// ---------------------------------------------------------------------------
__global__ __launch_bounds__(256) void wconvert(
    const float* __restrict__ src, __hip_bfloat16* __restrict__ dst,
    int K, int N)
{
    __shared__ float tile[64][65];
    int n0 = blockIdx.x * 64, k0 = blockIdx.y * 64;
    int c = threadIdx.x & 63, r = threadIdx.x >> 6;
    #pragma unroll 4
    for (int i = 0; i < 16; ++i)
        tile[r + i * 4][c] = src[(size_t)(k0 + r + i * 4) * N + n0 + c];
    __syncthreads();
    #pragma unroll 4
    for (int i = 0; i < 16; ++i)
        dst[(size_t)(n0 + r + i * 4) * K + k0 + c] =
            __float2bfloat16(tile[c][r + i * 4]);
}

// ---------------------------------------------------------------------------
// LayerNorm -> bf16
// ---------------------------------------------------------------------------
__global__ __launch_bounds__(256) void ln_kernel(
    const float* __restrict__ x, const float* __restrict__ g,
    const float* __restrict__ b, __hip_bfloat16* __restrict__ out)
{
    int row = blockIdx.x;
    const float* xr = x + (size_t)row * CDIM;
    __hip_bfloat16* orow = out + (size_t)row * CDIM;
    int t = threadIdx.x;
    float v0 = xr[t], v1 = xr[t + 256], v2 = xr[t + 512];
    float s  = v0 + v1 + v2;
    float s2 = v0*v0 + v1*v1 + v2*v2;
    #pragma unroll
    for (int off = 32; off; off >>= 1) {
        s  += __shfl_xor(s, off);
        s2 += __shfl_xor(s2, off);
    }
    __shared__ float red[10];
    int wave = t >> 6, lane = t & 63;
    if (lane == 0) { red[wave] = s; red[wave + 4] = s2; }
    __syncthreads();
    if (t == 0) {
        float ts  = red[0] + red[1] + red[2] + red[3];
        float ts2 = red[4] + red[5] + red[6] + red[7];
        float mu  = ts * (1.0f / CDIM);
        float var = ts2 * (1.0f / CDIM) - mu * mu;
        red[8] = mu;
        red[9] = rsqrtf(var + 1e-5f);
    }
    __syncthreads();
    float mu = red[8], rs = red[9];
    orow[t]       = __float2bfloat16((v0 - mu) * rs * g[t]       + b[t]);
    orow[t + 256] = __float2bfloat16((v1 - mu) * rs * g[t + 256] + b[t + 256]);
    orow[t + 512] = __float2bfloat16((v2 - mu) * rs * g[t + 512] + b[t + 512]);
}

// ---------------------------------------------------------------------------
// bf16 MFMA GEMM, BK=64 (two BK=32 sub-tiles per barrier pair).
// flags: bit0=gelu, bit1=bf16 out. K must be a multiple of 64.
// ---------------------------------------------------------------------------
__global__ __launch_bounds__(256) void mfma_gemm(
    const __hip_bfloat16* __restrict__ A,
    const __hip_bfloat16* __restrict__ Bt,
    const float* __restrict__ bias, const float* __restrict__ res,
    void* __restrict__ outv, int M, int Nc, int K, int flags)
{
    __shared__ __align__(16) __hip_bfloat16 As[2][128 * 32];
    __shared__ __align__(16) __hip_bfloat16 Bs[2][128 * 32];
    int t = threadIdx.x;
    int lane = t & 63, wv = t >> 6;
    int m0 = blockIdx.y * 128, n0 = blockIdx.x * 128;

    const __hip_bfloat16* Ag = A  + (size_t)(m0 + (t >> 2)) * K + (t & 3) * 8;
    const __hip_bfloat16* Bg = Bt + (size_t)(n0 + (t >> 2)) * K + (t & 3) * 8;
    __hip_bfloat16* lAs0 = As[0] + wv * 512;
    __hip_bfloat16* lBs0 = Bs[0] + wv * 512;
    __hip_bfloat16* lAs1 = As[1] + wv * 512;
    __hip_bfloat16* lBs1 = Bs[1] + wv * 512;

    int fr = lane & 15, fq = lane >> 4;
    int wm = (wv >> 1) * 64, wn = (wv & 1) * 64;

    f32x4 acc[4][4];
    #pragma unroll
    for (int i = 0; i < 4; ++i)
        #pragma unroll
        for (int j = 0; j < 4; ++j) acc[i][j] = (f32x4){0.f, 0.f, 0.f, 0.f};

    int ktiles = K >> 6;
    for (int k = 0; k < ktiles; ++k) {
        load_lds16(Ag,               lAs0);
        load_lds16(Ag + 64 * K,      lAs0 + 2048);
        load_lds16(Ag + 32,          lAs1);
        load_lds16(Ag + 32 + 64 * K, lAs1 + 2048);
        load_lds16(Bg,               lBs0);
        load_lds16(Bg + 64 * K,      lBs0 + 2048);
        load_lds16(Bg + 32,          lBs1);
        load_lds16(Bg + 32 + 64 * K, lBs1 + 2048);
        Ag += 64; Bg += 64;
        __syncthreads();
        #pragma unroll
        for (int kh = 0; kh < 2; ++kh) {
            const __hip_bfloat16* pa = As[kh] + (wm + fr) * 32 + fq * 8;
            const __hip_bfloat16* pb = Bs[kh] + (wn + fr) * 32 + fq * 8;
            bf16x8 af[4], bfv[4];
            #pragma unroll
            for (int tm = 0; tm < 4; ++tm)
                af[tm] = *(const bf16x8*)(pa + tm * 16 * 32);
            #pragma unroll
            for (int tn = 0; tn < 4; ++tn)
                bfv[tn] = *(const bf16x8*)(pb + tn * 16 * 32);
            #pragma unroll
            for (int tm = 0; tm < 4; ++tm)
                #pragma unroll
                for (int tn = 0; tn < 4; ++tn)
                    acc[tm][tn] = __builtin_amdgcn_mfma_f32_16x16x32_bf16(
                        af[tm], bfv[tn], acc[tm][tn], 0, 0, 0);
        }
        __syncthreads();
    }

    float* outf = (float*)outv;
    __hip_bfloat16* outb = (__hip_bfloat16*)outv;
    int gelu = flags & 1, obf = flags & 2;
    #pragma unroll
    for (int tm = 0; tm < 4; ++tm) {
        #pragma unroll
        for (int rg = 0; rg < 4; ++rg) {
            int gm = m0 + wm + tm * 16 + fq * 4 + rg;
            if (gm >= M) continue;
            #pragma unroll
            for (int tn = 0; tn < 4; ++tn) {
                int gn = n0 + wn + tn * 16 + fr;
                float v = acc[tm][tn][rg] + bias[gn];
                if (gelu) v = fast_gelu(v);
                if (res)  v += res[(size_t)gm * Nc + gn];
                if (obf) outb[(size_t)gm * Nc + gn] = __float2bfloat16(v);
                else     outf[(size_t)gm * Nc + gn] = v;
            }
        }
    }
}

// ---------------------------------------------------------------------------
// Repack qkv (bf16 [RTOT][2304]) into fragment-ordered blobs.
// ---------------------------------------------------------------------------
__global__ __launch_bounds__(256) void repack_qk(
    const u16* __restrict__ qkv, u16* __restrict__ Qp, u16* __restrict__ Kp)
{
    __shared__ u16 blob[1024];
    int mt = blockIdx.x, bh = blockIdx.y, sec = blockIdx.z;
    int b = bh / NH, h = bh % NH;
    int t = threadIdx.x;
    int r = t >> 4, d = (t & 15) * 4;
    int row = mt * 16 + r;
    ushort4 v = make_ushort4(0, 0, 0, 0);
    if (row < NTOK)
        v = *(const ushort4*)(qkv + (size_t)(b * NTOK + row) * 2304 + sec * 768 + h * 64 + d);
    int kf = d >> 5, fq = (d >> 3) & 3, jj = d & 7;
    u16* p = blob + kf * 512 + (fq * 16 + r) * 8 + jj;
    p[0] = v.x; p[1] = v.y; p[2] = v.z; p[3] = v.w;
    __syncthreads();
    u16* dst = (sec == 0 ? Qp : Kp) + (size_t)(bh * QT + mt) * 1024;
    *(ushort4*)(dst + t * 4) = *(const ushort4*)(blob + t * 4);
}

// ---------------------------------------------------------------------------
// Repack V transposed.
// ---------------------------------------------------------------------------
__global__ __launch_bounds__(256) void repack_v(
    const u16* __restrict__ qkv, u16* __restrict__ Vp)
{
    __shared__ u16 blob[4096];
    int jt = blockIdx.x, bh = blockIdx.y;
    int b = bh / NH, h = bh % NH;
    int t = threadIdx.x;
    int d = (t & 15) * 4;
    int dt = d >> 4;
    #pragma unroll
    for (int it = 0; it < 4; ++it) {
        int jr = (t >> 4) + it * 16;
        int row = jt * 64 + jr;
        ushort4 v = make_ushort4(0, 0, 0, 0);
        if (row < NTOK)
            v = *(const ushort4*)(qkv + (size_t)(b * NTOK + row) * 2304 + 1536 + h * 64 + d);
        int jf = jr >> 5, fq = (jr >> 3) & 3, jj = jr & 7;
        u16* p = blob + (dt * 2 + jf) * 512 + (fq * 16 + (d & 15)) * 8 + jj;
        p[0] = v.x; p[8] = v.y; p[16] = v.z; p[24] = v.w;
    }
    __syncthreads();
    #pragma unroll
    for (int dd = 0; dd < 4; ++dd) {
        size_t dstoff = ((size_t)(bh * 4 + dd) * 20 + jt * 2) * 512;
        *(ushort4*)(Vp + dstoff + t * 4) = *(const ushort4*)(blob + dd * 1024 + t * 4);
    }
}

// ---------------------------------------------------------------------------
// MFMA flash attention.
// ---------------------------------------------------------------------------
__global__ __launch_bounds__(256) void attn_mfma(
    const u16* __restrict__ Qp, const u16* __restrict__ Kp,
    const u16* __restrict__ Vp, __hip_bfloat16* __restrict__ outp)
{
    __shared__ __align__(16) u16 Ks[4096];
    __shared__ __align__(16) u16 Vs[4096];
    __shared__ __align__(16) u16 Ps[4 * 16 * 72];

    int bh = blockIdx.y, qc = blockIdx.x;
    int b = bh / NH, h = bh % NH;
    int t = threadIdx.x, lane = t & 63, wv = t >> 6;
    int fr = lane & 15, fq = lane >> 4;

    int mt = qc * 4 + wv;
    const u16* qbase = Qp + (size_t)(bh * QT + mt) * 1024 + lane * 8;
    bf16x8 qf0 = *(const bf16x8*)(qbase);
    bf16x8 qf1 = *(const bf16x8*)(qbase + 512);

    const u16* kg = Kp + (size_t)bh * (QT * 1024) + wv * 1024 + lane * 8;
    const u16* vg = Vp + ((size_t)(bh * 4 + wv) * 20) * 512 + lane * 8;
    u16* lK  = Ks + wv * 1024;
    u16* lV  = Vs + wv * 1024;
    u16* psw = Ps + wv * (16 * 72);

    f32x4 o[4];
    float m_r[4], l_r[4];
    #pragma unroll
    for (int i = 0; i < 4; ++i) {
        o[i] = (f32x4){0.f, 0.f, 0.f, 0.f};
        m_r[i] = -1e30f; l_r[i] = 0.f;
    }

    for (int kt = 0; kt < 10; ++kt) {
        load_lds16(kg + kt * 4096,       lK);
        load_lds16(kg + kt * 4096 + 512, lK + 512);
        load_lds16(vg + kt * 1024,       lV);
        load_lds16(vg + kt * 1024 + 512, lV + 512);
        __syncthreads();

        f32x4 sc[4];
        #pragma unroll
        for (int nt = 0; nt < 4; ++nt) {
            sc[nt] = (f32x4){0.f, 0.f, 0.f, 0.f};
            bf16x8 kf0 = *(const bf16x8*)(Ks + (nt * 2 + 0) * 512 + lane * 8);
            bf16x8 kf1 = *(const bf16x8*)(Ks + (nt * 2 + 1) * 512 + lane * 8);
            sc[nt] = __builtin_amdgcn_mfma_f32_16x16x32_bf16(qf0, kf0, sc[nt], 0, 0, 0);
            sc[nt] = __builtin_amdgcn_mfma_f32_16x16x32_bf16(qf1, kf1, sc[nt], 0, 0, 0);
        }

        int j0 = kt * 64;
        float p[4][4], rm[4];
        #pragma unroll
        for (int rg = 0; rg < 4; ++rg) rm[rg] = -1e30f;
        #pragma unroll
        for (int nt = 0; nt < 4; ++nt) {
            bool valid = (j0 + nt * 16 + fr) < NTOK;
            #pragma unroll
            for (int rg = 0; rg < 4; ++rg) {
                float sv = valid ? sc[nt][rg] * 0.125f : -1e30f;
                p[nt][rg] = sv;
                rm[rg] = fmaxf(rm[rg], sv);
            }
        }
        #pragma unroll
        for (int rg = 0; rg < 4; ++rg) {
            #pragma unroll
            for (int off = 1; off < 16; off <<= 1)
                rm[rg] = fmaxf(rm[rg], __shfl_xor(rm[rg], off));
        }
        float alpha[4], rs[4];
        #pragma unroll
        for (int rg = 0; rg < 4; ++rg) {
            float mn = fmaxf(m_r[rg], rm[rg]);
            alpha[rg] = __expf(m_r[rg] - mn);
            m_r[rg] = mn;
            rs[rg] = 0.f;
        }
        #pragma unroll
        for (int nt = 0; nt < 4; ++nt)
            #pragma unroll
            for (int rg = 0; rg < 4; ++rg) {
                float pv = __expf(p[nt][rg] - m_r[rg]);
                p[nt][rg] = pv;
                rs[rg] += pv;
            }
        #pragma unroll
        for (int rg = 0; rg < 4; ++rg) {
            #pragma unroll
            for (int off = 1; off < 16; off <<= 1)
                rs[rg] += __shfl_xor(rs[rg], off);
            l_r[rg] = l_r[rg] * alpha[rg] + rs[rg];
        }

        #pragma unroll
        for (int nt = 0; nt < 4; ++nt)
            #pragma unroll
            for (int rg = 0; rg < 4; ++rg) {
                __hip_bfloat16 hb = __float2bfloat16(p[nt][rg]);
                psw[(fq * 4 + rg) * 72 + nt * 16 + fr] = *(u16*)&hb;
            }
        #pragma unroll
        for (int dt = 0; dt < 4; ++dt)
            #pragma unroll
            for (int rg = 0; rg < 4; ++rg)
                o[dt][rg] *= alpha[rg];

        bf16x8 pf0 = *(const bf16x8*)(psw + fr * 72 + fq * 8);
        bf16x8 pf1 = *(const bf16x8*)(psw + fr * 72 + 32 + fq * 8);
        #pragma unroll
        for (int dt = 0; dt < 4; ++dt) {
            bf16x8 bv0 = *(const bf16x8*)(Vs + (dt * 2 + 0) * 512 + lane * 8);
            bf16x8 bv1 = *(const bf16x8*)(Vs + (dt * 2 + 1) * 512 + lane * 8);
            o[dt] = __builtin_amdgcn_mfma_f32_16x16x32_bf16(pf0, bv0, o[dt], 0, 0, 0);
            o[dt] = __builtin_amdgcn_mfma_f32_16x16x32_bf16(pf1, bv1, o[dt], 0, 0, 0);
        }
        __syncthreads();
    }

    #pragma unroll
    for (int rg = 0; rg < 4; ++rg) {
        int row = qc * 64 + wv * 16 + fq * 4 + rg;
        if (row < NTOK) {
            float rl = 1.0f / l_r[rg];
            #pragma unroll
            for (int dt = 0; dt < 4; ++dt)
                outp[(size_t)(b * NTOK + row) * CDIM + h * 64 + dt * 16 + fr] =
                    __float2bfloat16(o[dt][rg] * rl);
        }
    }
}

// ---------------------------------------------------------------------------
extern "C" void kernel_launch(void* const* d_in, const int* in_sizes, int n_in,
                              void* d_out, int out_size, void* d_ws, size_t ws_size,
                              hipStream_t stream)
{
    const float* x      = (const float*)d_in[0];
    const float* ln1_g  = (const float*)d_in[1];
    const float* ln1_b  = (const float*)d_in[2];
    const float* w_qkv  = (const float*)d_in[3];
    const float* b_qkv  = (const float*)d_in[4];
    const float* w_proj = (const float*)d_in[5];
    const float* b_proj = (const float*)d_in[6];
    const float* ln2_g  = (const float*)d_in[7];
    const float* ln2_b  = (const float*)d_in[8];
    const float* w_fc1  = (const float*)d_in[9];
    const float* b_fc1  = (const float*)d_in[10];
    const float* w_fc2  = (const float*)d_in[11];
    const float* b_fc2  = (const float*)d_in[12];
    float* out = (float*)d_out;

    char* w = (char*)d_ws;
    __hip_bfloat16* wqkv_t = (__hip_bfloat16*)w; w += (size_t)3*CDIM*CDIM*2;
    __hip_bfloat16* wproj_t= (__hip_bfloat16*)w; w += (size_t)CDIM*CDIM*2;
    __hip_bfloat16* wfc1_t = (__hip_bfloat16*)w; w += (size_t)HID*CDIM*2;
    __hip_bfloat16* wfc2_t = (__hip_bfloat16*)w; w += (size_t)CDIM*HID*2;
    __hip_bfloat16* h_bf   = (__hip_bfloat16*)w; w += (size_t)RPAD*CDIM*2;
    __hip_bfloat16* h3_bf  = (__hip_bfloat16*)w; w += (size_t)RPAD*HID*2;
    u16*            qkv_bf = (u16*)w;            w += (size_t)RTOT*3*CDIM*2;
    u16*            Qp     = (u16*)w;            w += (size_t)BH*QT*1024*2;
    u16*            Kp     = (u16*)w;            w += (size_t)BH*QT*1024*2;
    u16*            Vp     = (u16*)w;            w += (size_t)BH*4*20*512*2;

    // 0. weights -> bf16 transposed [N][K]
    wconvert<<<dim3(3*CDIM/64, CDIM/64), 256, 0, stream>>>(w_qkv,  wqkv_t, CDIM, 3*CDIM);
    wconvert<<<dim3(CDIM/64,   CDIM/64), 256, 0, stream>>>(w_proj, wproj_t, CDIM, CDIM);
    wconvert<<<dim3(HID/64,    CDIM/64), 256, 0, stream>>>(w_fc1,  wfc1_t, CDIM, HID);
    wconvert<<<dim3(CDIM/64,   HID/64),  256, 0, stream>>>(w_fc2,  wfc2_t, HID, CDIM);

    // 1. h = LN1(x)
    ln_kernel<<<RTOT, 256, 0, stream>>>(x, ln1_g, ln1_b, h_bf);
    // 2. qkv = h @ w_qkv + b_qkv  (bf16 out)
    mfma_gemm<<<dim3(3*CDIM/128, MT), 256, 0, stream>>>(
        h_bf, wqkv_t, b_qkv, nullptr, qkv_bf, RTOT, 3*CDIM, CDIM, 2);
    // 3. fragment-pack q/k/v
    repack_qk<<<dim3(QT, BH, 2), 256, 0, stream>>>(qkv_bf, Qp, Kp);
    repack_v <<<dim3(10, BH),    256, 0, stream>>>(qkv_bf, Vp);
    // 4. attention -> h_bf
    attn_mfma<<<dim3(10, BH), 256, 0, stream>>>(Qp, Kp, Vp, h_bf);
    // 5. x1 = x + attnout @ w_proj + b_proj -> d_out (fp32)
    mfma_gemm<<<dim3(CDIM/128, MT), 256, 0, stream>>>(
        h_bf, wproj_t, b_proj, x, out, RTOT, CDIM, CDIM, 0);
    // 6. h = LN2(x1)
    ln_kernel<<<RTOT, 256, 0, stream>>>(out, ln2_g, ln2_b, h_bf);
    // 7. h3 = gelu(h @ w_fc1 + b_fc1)  (bf16 out)
    mfma_gemm<<<dim3(HID/128, MT), 256, 0, stream>>>(
        h_bf, wfc1_t, b_fc1, nullptr, h3_bf, RTOT, HID, CDIM, 1 | 2);
    // 8. out = x1 + h3 @ w_fc2 + b_fc2  (fp32, res==out same-thread)
    mfma_gemm<<<dim3(CDIM/128, MT), 256, 0, stream>>>(
        h3_bf, wfc2_t, b_fc2, out, out, RTOT, CDIM, HID, 0);
}